// Round 8
// baseline (296.015 us; speedup 1.0000x reference)
//
#include <hip/hip_runtime.h>
#include <math.h>

// MultiHeadAttentionEinsum  B=2, S=2048, E=1024, H=16, D=64. Inputs fp32
// (proven rounds 3-7). Compute bf16 MFMA.
// r8: LDS-free attention (K/V frags direct from global, V key-swizzled in
// the V-GEMM epilogue so PV B-frags are contiguous b128 loads), 32 qrows/wave,
// register-double-buffered K. detect dispatch removed.

#define EMBED 1024
#define SEQ   2048
#define BATCH 2
#define NH    16
#define HD    64

typedef __attribute__((ext_vector_type(8))) short bf16x8;
typedef __attribute__((ext_vector_type(4))) short bf16x4;
typedef __attribute__((ext_vector_type(4))) float f32x4;

#define QSCALE 0.18033688f   // (1/sqrt(64)) * log2(e), folded into Q projection

__device__ inline unsigned short f2bf(float f) {
  unsigned int u = __builtin_bit_cast(unsigned int, f);
  u += 0x7fffu + ((u >> 16) & 1u);
  return (unsigned short)(u >> 16);
}

__device__ inline void async_cp16(const void* g, void* l) {
  __builtin_amdgcn_global_load_lds(
      (const __attribute__((address_space(1))) unsigned int*)g,
      (__attribute__((address_space(3))) unsigned int*)l, 16, 0, 0);
}

// V key swizzle within each 32-key group along S:
//   stored position p = 8q + 4h + r  holds  key = 16h + 4q + r
// so the PV A-operand slot k = q*8 + j (j = 4h + r) matches key 16h+4q+r,
// making the B-frag (V^T row) a contiguous 8-key b128 at offset q*8.
__device__ inline int vswz_src(int p) {     // position -> source key (same 32-group)
  return (p & ~31) + 16 * ((p >> 2) & 1) + 4 * ((p >> 3) & 3) + (p & 3);
}
__device__ inline int vswz_pos(int s) {     // key -> stored position
  return (s & ~31) + 8 * ((s >> 2) & 3) + 4 * ((s >> 4) & 1) + (s & 3);
}

// ---- fp32->bf16 pack of xq,xk,xv + Wq,Wk,Wv,Wo ----
struct PackPtrs {
  const float* src[7];
  unsigned short* dst[7];
};
__global__ __launch_bounds__(256) void pack_all(PackPtrs p) {
  int ci = blockIdx.x * 256 + threadIdx.x;
  int t, rel;
  if (ci < 1572864) { t = ci / 524288; rel = ci - t * 524288; }
  else { int r = ci - 1572864; int w = r / 131072; t = 3 + w; rel = r - w * 131072; }
  size_t off = (size_t)rel * 8;
  const float* s = p.src[t] + off;
  bf16x8 v;
#pragma unroll
  for (int e = 0; e < 8; ++e) v[e] = (short)f2bf(s[e]);
  *(bf16x8*)(p.dst[t] + off) = v;
}

// ---- fused QKV GEMM: 128x128 tile (m97 structure), grid (32, 8, 3) ----
// z=0: Q [B,H,S,D] * QSCALE; z=1: K [B,H,S,D]; z=2: V [B,H,D,S'] key-swizzled
struct QkvArgs {
  const unsigned short* A[3];
  const unsigned short* W[3];
  unsigned short* out[3];
};
__global__ __launch_bounds__(256) void gemm_qkv(QkvArgs args) {
  __shared__ __align__(16) unsigned short smem[16640];  // As 4096 | Bs 4096 ; Ts reuses
  unsigned short* As = smem;
  unsigned short* Bs = smem + 4096;

  const int z = blockIdx.z;
  const unsigned short* A = args.A[z];
  const unsigned short* Bw = args.W[z];
  unsigned short* out = args.out[z];

  const int tid = threadIdx.x, lane = tid & 63, wave = tid >> 6;
  const int wm = wave >> 1, wn = wave & 1;
  const int q = lane >> 4, c = lane & 15;
  const int m0 = blockIdx.x * 128, n0 = blockIdx.y * 128;

  f32x4 acc[4][4];
#pragma unroll
  for (int i = 0; i < 4; ++i)
#pragma unroll
    for (int j = 0; j < 4; ++j) acc[i][j] = (f32x4){0.f, 0.f, 0.f, 0.f};

  for (int k0 = 0; k0 < EMBED; k0 += 32) {
    __syncthreads();
#pragma unroll
    for (int jj = 0; jj < 2; ++jj) {
      int ci = jj * 256 + tid;
      async_cp16(A + (size_t)(m0 + (ci >> 2)) * EMBED + k0 + (ci & 3) * 8,
                 (void*)(As + (jj * 256 + wave * 64) * 8));
      async_cp16(Bw + (size_t)(n0 + (ci >> 2)) * EMBED + k0 + (ci & 3) * 8,
                 (void*)(Bs + (jj * 256 + wave * 64) * 8));
    }
    __syncthreads();

    bf16x8 af[4], bfr[4];
#pragma unroll
    for (int i = 0; i < 4; ++i)
      af[i] = *(const bf16x8*)(As + (wm * 64 + i * 16 + c) * 32 + q * 8);
#pragma unroll
    for (int j = 0; j < 4; ++j)
      bfr[j] = *(const bf16x8*)(Bs + (wn * 64 + j * 16 + c) * 32 + q * 8);
#pragma unroll
    for (int i = 0; i < 4; ++i)
#pragma unroll
      for (int j = 0; j < 4; ++j)
        acc[i][j] = __builtin_amdgcn_mfma_f32_16x16x32_bf16(af[i], bfr[j], acc[i][j], 0, 0, 0);
  }

  if (z < 2) {
    const float sc = (z == 0) ? QSCALE : 1.0f;
#pragma unroll
    for (int i = 0; i < 4; ++i)
#pragma unroll
      for (int j = 0; j < 4; ++j)
#pragma unroll
        for (int r = 0; r < 4; ++r) {
          int m = m0 + wm * 64 + i * 16 + q * 4 + r;
          int col = n0 + wn * 64 + j * 16 + c;
          int b = m >> 11, s = m & 2047, h = col >> 6, d = col & 63;
          out[(size_t)((b * NH + h) * SEQ + s) * HD + d] = f2bf(acc[i][j][r] * sc);
        }
  } else {
    // V: transpose 128(s) x 128(d, 2 heads) tile through LDS -> [B,H,D,S'] swizzled
    __syncthreads();
#pragma unroll
    for (int i = 0; i < 4; ++i)
#pragma unroll
      for (int j = 0; j < 4; ++j)
#pragma unroll
        for (int r = 0; r < 4; ++r)
          smem[(wm * 64 + i * 16 + q * 4 + r) * 130 + wn * 64 + j * 16 + c] =
              f2bf(acc[i][j][r]);
    __syncthreads();
    int n = tid >> 1;                 // 0..127 local d-col
    int sh = (tid & 1) * 64;          // s half
    int b = m0 >> 11, s0l = m0 & 2047;
    int h = blockIdx.y * 2 + (n >> 6), d = n & 63;
    unsigned short* dst = out + (size_t)((b * NH + h) * HD + d) * SEQ + s0l + sh;
#pragma unroll
    for (int g = 0; g < 8; ++g) {
      bf16x8 v;
#pragma unroll
      for (int e = 0; e < 8; ++e)
        v[e] = (short)smem[vswz_src(sh + g * 8 + e) * 130 + n];
      *(bf16x8*)(dst + g * 8) = v;
    }
  }
}

// ---- out-projection GEMM: 128x128 tile, grid (32, 8); A bf16, out/bias fp32 ----
__global__ __launch_bounds__(256) void gemm_out(
    const unsigned short* __restrict__ A,
    const unsigned short* __restrict__ Bw,
    const float* __restrict__ bias,
    float* __restrict__ out)
{
  __shared__ __align__(16) unsigned short As[4096];
  __shared__ __align__(16) unsigned short Bs[4096];

  const int tid = threadIdx.x, lane = tid & 63, wave = tid >> 6;
  const int wm = wave >> 1, wn = wave & 1;
  const int q = lane >> 4, c = lane & 15;
  const int m0 = blockIdx.x * 128, n0 = blockIdx.y * 128;

  f32x4 acc[4][4];
#pragma unroll
  for (int i = 0; i < 4; ++i)
#pragma unroll
    for (int j = 0; j < 4; ++j) acc[i][j] = (f32x4){0.f, 0.f, 0.f, 0.f};

  for (int k0 = 0; k0 < EMBED; k0 += 32) {
    __syncthreads();
#pragma unroll
    for (int jj = 0; jj < 2; ++jj) {
      int ci = jj * 256 + tid;
      async_cp16(A + (size_t)(m0 + (ci >> 2)) * EMBED + k0 + (ci & 3) * 8,
                 (void*)(As + (jj * 256 + wave * 64) * 8));
      async_cp16(Bw + (size_t)(n0 + (ci >> 2)) * EMBED + k0 + (ci & 3) * 8,
                 (void*)(Bs + (jj * 256 + wave * 64) * 8));
    }
    __syncthreads();

    bf16x8 af[4], bfr[4];
#pragma unroll
    for (int i = 0; i < 4; ++i)
      af[i] = *(const bf16x8*)(As + (wm * 64 + i * 16 + c) * 32 + q * 8);
#pragma unroll
    for (int j = 0; j < 4; ++j)
      bfr[j] = *(const bf16x8*)(Bs + (wn * 64 + j * 16 + c) * 32 + q * 8);
#pragma unroll
    for (int i = 0; i < 4; ++i)
#pragma unroll
      for (int j = 0; j < 4; ++j)
        acc[i][j] = __builtin_amdgcn_mfma_f32_16x16x32_bf16(af[i], bfr[j], acc[i][j], 0, 0, 0);
  }

#pragma unroll
  for (int i = 0; i < 4; ++i)
#pragma unroll
    for (int j = 0; j < 4; ++j)
#pragma unroll
      for (int r = 0; r < 4; ++r) {
        int m = m0 + wm * 64 + i * 16 + q * 4 + r;
        int col = n0 + wn * 64 + j * 16 + c;
        float v = acc[i][j][r] + bias[col];
        if (isnan(v)) v = 777.0f;     // marker
        out[(size_t)m * EMBED + col] = v;
      }
}

// ---- flash attention v5: LDS-free. Grid (16,16,2)=512 blocks, 4 waves x 32 qrows.
// K frags: direct coalesced global (16 rows x 128B slab / subtile).
// V frags: direct b128 global from key-swizzled V^T.
// K register-double-buffered across 64-key iterations. No barriers, no LDS.
__global__ __launch_bounds__(256, 2) void attn_kernel(
    const unsigned short* __restrict__ Qb,
    const unsigned short* __restrict__ Kb,
    const unsigned short* __restrict__ Vtb,
    unsigned short* __restrict__ Ob)
{
  const int tid = threadIdx.x;
  const int lane = tid & 63;
  const int wave = tid >> 6;
  const int q = lane >> 4, c = lane & 15;
  const int b = blockIdx.z, h = blockIdx.y;
  const int q0w = blockIdx.x * 128 + wave * 32;

  const unsigned short* Qh = Qb + ((size_t)(b * NH + h) * SEQ) * HD;
  const unsigned short* Kh = Kb + ((size_t)(b * NH + h) * SEQ) * HD;
  const unsigned short* Vh = Vtb + ((size_t)(b * NH + h) * HD) * SEQ;

  // Q B-operand frags for 2 q-subtiles (n=lane&15=qrow, k=d=quad*8+j)
  bf16x8 qfl[2], qfh[2];
#pragma unroll
  for (int qs = 0; qs < 2; ++qs) {
    qfl[qs] = *(const bf16x8*)(Qh + (q0w + qs * 16 + c) * HD + q * 8);
    qfh[qs] = *(const bf16x8*)(Qh + (q0w + qs * 16 + c) * HD + 32 + q * 8);
  }

  f32x4 o[2][4];
#pragma unroll
  for (int qs = 0; qs < 2; ++qs)
#pragma unroll
    for (int t = 0; t < 4; ++t) o[qs][t] = (f32x4){0.f, 0.f, 0.f, 0.f};
  float l[2] = {0.f, 0.f};

  bf16x8 k0b[2][4], k1b[2][4];
  // preload K tile 0
#pragma unroll
  for (int s = 0; s < 4; ++s) {
    k0b[0][s] = *(const bf16x8*)(Kh + (size_t)(s * 16 + c) * HD + q * 8);
    k1b[0][s] = *(const bf16x8*)(Kh + (size_t)(s * 16 + c) * HD + 32 + q * 8);
  }

#define ATTN_BODY(KT, CUR, NXT)                                                   \
  {                                                                               \
    bf16x8 vb[4][2];                                                              \
    _Pragma("unroll")                                                             \
    for (int t = 0; t < 4; ++t)                                                   \
      _Pragma("unroll")                                                           \
      for (int g = 0; g < 2; ++g)                                                 \
        vb[t][g] = *(const bf16x8*)(Vh + (size_t)(t * 16 + c) * SEQ +             \
                                    (KT) * 64 + g * 32 + q * 8);                  \
    if ((KT) + 1 < SEQ / 64) {                                                    \
      const size_t kb = (size_t)((KT) + 1) * 64;                                  \
      _Pragma("unroll")                                                           \
      for (int s = 0; s < 4; ++s) {                                               \
        k0b[NXT][s] = *(const bf16x8*)(Kh + (kb + s * 16 + c) * HD + q * 8);      \
        k1b[NXT][s] = *(const bf16x8*)(Kh + (kb + s * 16 + c) * HD + 32 + q * 8); \
      }                                                                           \
    }                                                                             \
    bf16x4 pk[2][4];                                                              \
    _Pragma("unroll")                                                             \
    for (int s = 0; s < 4; ++s) {                                                 \
      _Pragma("unroll")                                                           \
      for (int qs = 0; qs < 2; ++qs) {                                            \
        f32x4 z = {0.f, 0.f, 0.f, 0.f};                                           \
        z = __builtin_amdgcn_mfma_f32_16x16x32_bf16(k0b[CUR][s], qfl[qs], z, 0, 0, 0); \
        z = __builtin_amdgcn_mfma_f32_16x16x32_bf16(k1b[CUR][s], qfh[qs], z, 0, 0, 0); \
        _Pragma("unroll")                                                         \
        for (int r = 0; r < 4; ++r) {                                             \
          float pv = __builtin_amdgcn_exp2f(z[r]);                                \
          l[qs] += pv;                                                            \
          pk[qs][s][r] = (short)(__builtin_bit_cast(unsigned int, pv) >> 16);     \
        }                                                                         \
      }                                                                           \
    }                                                                             \
    _Pragma("unroll")                                                             \
    for (int g = 0; g < 2; ++g)                                                   \
      _Pragma("unroll")                                                           \
      for (int t = 0; t < 4; ++t)                                                 \
        _Pragma("unroll")                                                         \
        for (int qs = 0; qs < 2; ++qs) {                                          \
          bf16x8 pf;                                                              \
          _Pragma("unroll")                                                       \
          for (int e = 0; e < 4; ++e) {                                           \
            pf[e] = pk[qs][2 * (g)][e];                                           \
            pf[4 + e] = pk[qs][2 * (g) + 1][e];                                   \
          }                                                                       \
          o[qs][t] = __builtin_amdgcn_mfma_f32_16x16x32_bf16(pf, vb[t][g],        \
                                                             o[qs][t], 0, 0, 0); \
        }                                                                         \
  }

  for (int kt = 0; kt < SEQ / 64; kt += 2) {
    ATTN_BODY(kt, 0, 1)
    ATTN_BODY(kt + 1, 1, 0)
  }
#undef ATTN_BODY

#pragma unroll
  for (int qs = 0; qs < 2; ++qs) {
    float ls = l[qs];
    ls += __shfl_xor(ls, 16);
    ls += __shfl_xor(ls, 32);
    float lf[4];
#pragma unroll
    for (int r = 0; r < 4; ++r) lf[r] = 1.f / __shfl(ls, q * 4 + r);
#pragma unroll
    for (int t = 0; t < 4; ++t)
#pragma unroll
      for (int r = 0; r < 4; ++r) {
        int srow = q0w + qs * 16 + q * 4 + r;
        int col = h * HD + t * 16 + c;
        float val = o[qs][t][r] * lf[r];
        if (isnan(val)) val = 77.0f;  // marker
        Ob[((size_t)(b * SEQ + srow)) * EMBED + col] = f2bf(val);
      }
  }
}

// ---- fallback GEMM (direct global loads; fp32 inputs) ----
__device__ inline bf16x8 load8f(const float* f) {
  bf16x8 r;
#pragma unroll
  for (int i = 0; i < 8; ++i) r[i] = (short)f2bf(f[i]);
  return r;
}
__global__ __launch_bounds__(256) void gemm_bt(
    const void* __restrict__ A, const void* __restrict__ Bw,
    const float* __restrict__ bias, void* __restrict__ out,
    int mode, float scale)
{
  const int lane = threadIdx.x & 63;
  const int wave = threadIdx.x >> 6;
  const int tile = blockIdx.x * 4 + wave;
  const int mt = tile >> 4, nt = tile & 15;
  const int q = lane >> 4, c = lane & 15;
  const int m0 = mt * 16, n0 = nt * 64;

  f32x4 acc[4];
#pragma unroll
  for (int t = 0; t < 4; ++t) acc[t] = (f32x4){0.f, 0.f, 0.f, 0.f};

  for (int k0 = 0; k0 < EMBED; k0 += 32) {
    bf16x8 a = (mode == 0)
        ? *(const bf16x8*)((const unsigned short*)A + (m0 + c) * EMBED + k0 + q * 8)
        : load8f((const float*)A + (m0 + c) * EMBED + k0 + q * 8);
#pragma unroll
    for (int t = 0; t < 4; ++t) {
      bf16x8 b = load8f((const float*)Bw + (size_t)(n0 + t * 16 + c) * EMBED + k0 + q * 8);
      acc[t] = __builtin_amdgcn_mfma_f32_16x16x32_bf16(a, b, acc[t], 0, 0, 0);
    }
  }
#pragma unroll
  for (int t = 0; t < 4; ++t)
#pragma unroll
    for (int r = 0; r < 4; ++r) {
      float v = acc[t][r] * scale;
      int row = m0 + q * 4 + r, col = n0 + t * 16 + c;
      if (mode == 0) {
        v += bias[col];
        ((float*)out)[(size_t)row * EMBED + col] = v;
      } else {
        int b = row >> 11, s = row & 2047, h = col >> 6, d = col & 63;
        if (mode == 1)
          ((unsigned short*)out)[(size_t)((b * NH + h) * SEQ + s) * HD + d] = f2bf(v);
        else
          ((unsigned short*)out)[(size_t)((b * NH + h) * HD + d) * SEQ + vswz_pos(s)] = f2bf(v);
      }
    }
}

extern "C" void kernel_launch(void* const* d_in, const int* in_sizes, int n_in,
                              void* d_out, int out_size, void* d_ws, size_t ws_size,
                              hipStream_t stream) {
  const float* xq = (const float*)d_in[0];
  const float* xk = (const float*)d_in[1];
  const float* xv = (const float*)d_in[2];
  const float* Wq = (const float*)d_in[3];
  const float* Wk = (const float*)d_in[4];
  const float* Wv = (const float*)d_in[5];
  const float* Wo = (const float*)d_in[6];
  const float* bo = (const float*)d_in[7];

  const size_t NEL = (size_t)BATCH * SEQ * EMBED;   // 4,194,304
  const size_t WEL = (size_t)EMBED * EMBED;         // 1,048,576
  unsigned short* base = (unsigned short*)d_ws;

  unsigned short* Xq = base;
  unsigned short* Xk = Xq + NEL;
  unsigned short* Xv = Xk + NEL;
  unsigned short* Wqb = Xv + NEL;
  unsigned short* Wkb = Wqb + WEL;
  unsigned short* Wvb = Wkb + WEL;
  unsigned short* Wob = Wvb + WEL;
  unsigned short* Q  = Wob + WEL;
  unsigned short* K  = Q + NEL;
  unsigned short* Vt = K + NEL;
  unsigned short* AO = Xq;                  // alias: Xq dead after QKV GEMM
  size_t need = (size_t)(6 * NEL + 4 * WEL) * sizeof(unsigned short);

  if (ws_size >= need) {
    PackPtrs pp;
    pp.src[0] = xq; pp.src[1] = xk; pp.src[2] = xv;
    pp.src[3] = Wq; pp.src[4] = Wk; pp.src[5] = Wv; pp.src[6] = Wo;
    pp.dst[0] = Xq; pp.dst[1] = Xk; pp.dst[2] = Xv;
    pp.dst[3] = Wqb; pp.dst[4] = Wkb; pp.dst[5] = Wvb; pp.dst[6] = Wob;
    pack_all<<<8192, 256, 0, stream>>>(pp);

    QkvArgs qa;
    qa.A[0] = Xq; qa.A[1] = Xk; qa.A[2] = Xv;
    qa.W[0] = Wqb; qa.W[1] = Wkb; qa.W[2] = Wvb;
    qa.out[0] = Q; qa.out[1] = K; qa.out[2] = Vt;
    gemm_qkv<<<dim3(32, 8, 3), 256, 0, stream>>>(qa);
    attn_kernel<<<dim3(16, NH, BATCH), 256, 0, stream>>>(Q, K, Vt, AO);
    gemm_out<<<dim3(32, 8), 256, 0, stream>>>(AO, Wob, bo, (float*)d_out);
  } else {
    // compact fallback: 33.6 MB (Q,K,Vt,AO bf16), fp32 read in-GEMM
    unsigned short* Qf  = base;
    unsigned short* Kf  = Qf + NEL;
    unsigned short* Vtf = Kf + NEL;
    unsigned short* AOf = Vtf + NEL;
    dim3 gblk(1024, 1, 1);
    gemm_bt<<<gblk, 256, 0, stream>>>(xq, Wq, nullptr, Qf, 1, QSCALE);
    gemm_bt<<<gblk, 256, 0, stream>>>(xk, Wk, nullptr, Kf, 1, 1.0f);
    gemm_bt<<<gblk, 256, 0, stream>>>(xv, Wv, nullptr, Vtf, 2, 1.0f);
    attn_kernel<<<dim3(16, NH, BATCH), 256, 0, stream>>>(Qf, Kf, Vtf, AOf);
    gemm_bt<<<gblk, 256, 0, stream>>>(AOf, Wo, bo, d_out, 0, 1.0f);
  }
}

// Round 9
// 294.452 us; speedup vs baseline: 1.0053x; 1.0053x over previous
//
#include <hip/hip_runtime.h>
#include <math.h>

// MultiHeadAttentionEinsum  B=2, S=2048, E=1024, H=16, D=64. Inputs fp32.
// r9: attn = r7 K-LDS-dbuf skeleton + direct-global swizzled V (r8-proven);
// GEMMs BK=64 with XOR-swizzled LDS (conflict-free, coalescing preserved);
// gemm_out 64x128 tiles (2 blocks/CU).

#define EMBED 1024
#define SEQ   2048
#define BATCH 2
#define NH    16
#define HD    64

typedef __attribute__((ext_vector_type(8))) short bf16x8;
typedef __attribute__((ext_vector_type(4))) short bf16x4;
typedef __attribute__((ext_vector_type(4))) float f32x4;

#define QSCALE 0.18033688f   // (1/sqrt(64)) * log2(e), folded into Q projection

__device__ inline unsigned short f2bf(float f) {
  unsigned int u = __builtin_bit_cast(unsigned int, f);
  u += 0x7fffu + ((u >> 16) & 1u);
  return (unsigned short)(u >> 16);
}

__device__ inline void async_cp16(const void* g, void* l) {
  __builtin_amdgcn_global_load_lds(
      (const __attribute__((address_space(1))) unsigned int*)g,
      (__attribute__((address_space(3))) unsigned int*)l, 16, 0, 0);
}

// V key swizzle within each 32-key group along S (r8-proven):
// stored position p = 8q + 4h + r holds key = 16h + 4q + r, so PV A-slot
// k=q*8+j matches a contiguous b128 V^T row read at offset q*8.
__device__ inline int vswz_src(int p) {
  return (p & ~31) + 16 * ((p >> 2) & 1) + 4 * ((p >> 3) & 3) + (p & 3);
}
__device__ inline int vswz_pos(int s) {
  return (s & ~31) + 8 * ((s >> 2) & 3) + 4 * ((s >> 4) & 1) + (s & 3);
}

// ---- fp32->bf16 pack ----
struct PackPtrs {
  const float* src[7];
  unsigned short* dst[7];
};
__global__ __launch_bounds__(256) void pack_all(PackPtrs p) {
  int ci = blockIdx.x * 256 + threadIdx.x;
  int t, rel;
  if (ci < 1572864) { t = ci / 524288; rel = ci - t * 524288; }
  else { int r = ci - 1572864; int w = r / 131072; t = 3 + w; rel = r - w * 131072; }
  size_t off = (size_t)rel * 8;
  const float* s = p.src[t] + off;
  bf16x8 v;
#pragma unroll
  for (int e = 0; e < 8; ++e) v[e] = (short)f2bf(s[e]);
  *(bf16x8*)(p.dst[t] + off) = v;
}

// ---- fused QKV GEMM: 128x128 tile, BK=64, XOR-swizzled LDS. grid (32,8,3) ----
// z=0: Q [B,H,S,D]*QSCALE; z=1: K [B,H,S,D]; z=2: V [B,H,D,S'] key-swizzled
struct QkvArgs {
  const unsigned short* A[3];
  const unsigned short* W[3];
  unsigned short* out[3];
};
__global__ __launch_bounds__(256) void gemm_qkv(QkvArgs args) {
  __shared__ __align__(16) unsigned short smem[16640];  // As 8192 | Bs 8192; Ts reuses
  unsigned short* As = smem;
  unsigned short* Bs = smem + 8192;

  const int z = blockIdx.z;
  const unsigned short* A = args.A[z];
  const unsigned short* Bw = args.W[z];
  unsigned short* out = args.out[z];

  const int tid = threadIdx.x, lane = tid & 63, wave = tid >> 6;
  const int wm = wave >> 1, wn = wave & 1;
  const int q = lane >> 4, c = lane & 15;
  const int m0 = blockIdx.x * 128, n0 = blockIdx.y * 128;

  f32x4 acc[4][4];
#pragma unroll
  for (int i = 0; i < 4; ++i)
#pragma unroll
    for (int j = 0; j < 4; ++j) acc[i][j] = (f32x4){0.f, 0.f, 0.f, 0.f};

  for (int k0 = 0; k0 < EMBED; k0 += 64) {
    __syncthreads();
    // 128x64 tiles: 1024 16B-chunks each; chunk-in-row XOR-swizzled by row&7.
#pragma unroll
    for (int jj = 0; jj < 4; ++jj) {
      int ci = jj * 256 + tid;
      int row = ci >> 3, sc = ((ci & 7) ^ (row & 7)) * 8;
      async_cp16(A + (size_t)(m0 + row) * EMBED + k0 + sc,
                 (void*)(As + (jj * 256 + wave * 64) * 8));
      async_cp16(Bw + (size_t)(n0 + row) * EMBED + k0 + sc,
                 (void*)(Bs + (jj * 256 + wave * 64) * 8));
    }
    __syncthreads();

#pragma unroll
    for (int kk = 0; kk < 2; ++kk) {
      bf16x8 af[4], bfr[4];
#pragma unroll
      for (int i = 0; i < 4; ++i)
        af[i] = *(const bf16x8*)(As + (wm * 64 + i * 16 + c) * 64 +
                                 (((kk * 4 + q) ^ (c & 7)) * 8));
#pragma unroll
      for (int j = 0; j < 4; ++j)
        bfr[j] = *(const bf16x8*)(Bs + (wn * 64 + j * 16 + c) * 64 +
                                  (((kk * 4 + q) ^ (c & 7)) * 8));
#pragma unroll
      for (int i = 0; i < 4; ++i)
#pragma unroll
        for (int j = 0; j < 4; ++j)
          acc[i][j] = __builtin_amdgcn_mfma_f32_16x16x32_bf16(af[i], bfr[j], acc[i][j], 0, 0, 0);
    }
  }

  if (z < 2) {
    const float sc = (z == 0) ? QSCALE : 1.0f;
#pragma unroll
    for (int i = 0; i < 4; ++i)
#pragma unroll
      for (int j = 0; j < 4; ++j)
#pragma unroll
        for (int r = 0; r < 4; ++r) {
          int m = m0 + wm * 64 + i * 16 + q * 4 + r;
          int col = n0 + wn * 64 + j * 16 + c;
          int b = m >> 11, s = m & 2047, h = col >> 6, d = col & 63;
          out[(size_t)((b * NH + h) * SEQ + s) * HD + d] = f2bf(acc[i][j][r] * sc);
        }
  } else {
    __syncthreads();
#pragma unroll
    for (int i = 0; i < 4; ++i)
#pragma unroll
      for (int j = 0; j < 4; ++j)
#pragma unroll
        for (int r = 0; r < 4; ++r)
          smem[(wm * 64 + i * 16 + q * 4 + r) * 130 + wn * 64 + j * 16 + c] =
              f2bf(acc[i][j][r]);
    __syncthreads();
    int n = tid >> 1;
    int sh = (tid & 1) * 64;
    int b = m0 >> 11, s0l = m0 & 2047;
    int h = blockIdx.y * 2 + (n >> 6), d = n & 63;
    unsigned short* dst = out + (size_t)((b * NH + h) * HD + d) * SEQ + s0l + sh;
#pragma unroll
    for (int g = 0; g < 8; ++g) {
      bf16x8 v;
#pragma unroll
      for (int e = 0; e < 8; ++e)
        v[e] = (short)smem[vswz_src(sh + g * 8 + e) * 130 + n];
      *(bf16x8*)(dst + g * 8) = v;
    }
  }
}

// ---- out-projection: 64x128 tile, BK=64, swizzled LDS. grid (64,8) = 512 blocks ----
__global__ __launch_bounds__(256) void gemm_out(
    const unsigned short* __restrict__ A,
    const unsigned short* __restrict__ Bw,
    const float* __restrict__ bias,
    float* __restrict__ out)
{
  __shared__ __align__(16) unsigned short As[4096];   // 64x64
  __shared__ __align__(16) unsigned short Bs[8192];   // 128x64

  const int tid = threadIdx.x, lane = tid & 63, wave = tid >> 6;
  const int wm = wave >> 1, wn = wave & 1;
  const int q = lane >> 4, c = lane & 15;
  const int m0 = blockIdx.x * 64, n0 = blockIdx.y * 128;

  f32x4 acc[2][4];
#pragma unroll
  for (int i = 0; i < 2; ++i)
#pragma unroll
    for (int j = 0; j < 4; ++j) acc[i][j] = (f32x4){0.f, 0.f, 0.f, 0.f};

  for (int k0 = 0; k0 < EMBED; k0 += 64) {
    __syncthreads();
#pragma unroll
    for (int jj = 0; jj < 2; ++jj) {
      int ci = jj * 256 + tid;
      int row = ci >> 3, sc = ((ci & 7) ^ (row & 7)) * 8;
      async_cp16(A + (size_t)(m0 + row) * EMBED + k0 + sc,
                 (void*)(As + (jj * 256 + wave * 64) * 8));
    }
#pragma unroll
    for (int jj = 0; jj < 4; ++jj) {
      int ci = jj * 256 + tid;
      int row = ci >> 3, sc = ((ci & 7) ^ (row & 7)) * 8;
      async_cp16(Bw + (size_t)(n0 + row) * EMBED + k0 + sc,
                 (void*)(Bs + (jj * 256 + wave * 64) * 8));
    }
    __syncthreads();

#pragma unroll
    for (int kk = 0; kk < 2; ++kk) {
      bf16x8 af[2], bfr[4];
#pragma unroll
      for (int i = 0; i < 2; ++i)
        af[i] = *(const bf16x8*)(As + (wm * 32 + i * 16 + c) * 64 +
                                 (((kk * 4 + q) ^ (c & 7)) * 8));
#pragma unroll
      for (int j = 0; j < 4; ++j)
        bfr[j] = *(const bf16x8*)(Bs + (wn * 64 + j * 16 + c) * 64 +
                                  (((kk * 4 + q) ^ (c & 7)) * 8));
#pragma unroll
      for (int i = 0; i < 2; ++i)
#pragma unroll
        for (int j = 0; j < 4; ++j)
          acc[i][j] = __builtin_amdgcn_mfma_f32_16x16x32_bf16(af[i], bfr[j], acc[i][j], 0, 0, 0);
    }
  }

#pragma unroll
  for (int i = 0; i < 2; ++i)
#pragma unroll
    for (int j = 0; j < 4; ++j)
#pragma unroll
      for (int r = 0; r < 4; ++r) {
        int m = m0 + wm * 32 + i * 16 + q * 4 + r;
        int col = n0 + wn * 64 + j * 16 + c;
        float v = acc[i][j][r] + bias[col];
        if (isnan(v)) v = 777.0f;     // marker
        out[(size_t)m * EMBED + col] = v;
      }
}

// ---- flash attention v6: K LDS-dbuf (r7-proven) + direct-global swizzled V.
// Grid (32,16,2)=1024 blocks, 4 waves x 16 qrows. One barrier/iter.
__global__ __launch_bounds__(256, 4) void attn_kernel(
    const unsigned short* __restrict__ Qb,
    const unsigned short* __restrict__ Kb,
    const unsigned short* __restrict__ Vtb,
    unsigned short* __restrict__ Ob)
{
  __shared__ __align__(16) unsigned short Kt[2][64][72];

  const int tid = threadIdx.x;
  const int lane = tid & 63;
  const int wave = tid >> 6;
  const int q = lane >> 4, c = lane & 15;
  const int b = blockIdx.z, h = blockIdx.y;
  const int q0 = blockIdx.x * 64 + wave * 16;

  const unsigned short* Qh = Qb + ((size_t)(b * NH + h) * SEQ) * HD;
  const unsigned short* Kh = Kb + ((size_t)(b * NH + h) * SEQ) * HD;
  const unsigned short* Vh = Vtb + ((size_t)(b * NH + h) * HD) * SEQ;

  bf16x8 qfl = *(const bf16x8*)(Qh + (q0 + c) * HD + q * 8);
  bf16x8 qfh = *(const bf16x8*)(Qh + (q0 + c) * HD + 32 + q * 8);

  f32x4 o[4];
#pragma unroll
  for (int t = 0; t < 4; ++t) o[t] = (f32x4){0.f, 0.f, 0.f, 0.f};
  float l = 0.f;

  const int r0 = tid >> 3;          // 0..31
  const int ch0 = (tid & 7) * 8;

  bf16x8 kr0, kr1;
  kr0 = *(const bf16x8*)(Kh + (size_t)r0 * HD + ch0);
  kr1 = *(const bf16x8*)(Kh + (size_t)(32 + r0) * HD + ch0);
  *(bf16x8*)(&Kt[0][r0][ch0]) = kr0;
  *(bf16x8*)(&Kt[0][32 + r0][ch0]) = kr1;

  for (int kt = 0; kt < SEQ / 64; ++kt) {
    const int p = kt & 1;
    __syncthreads();
    if (kt + 1 < SEQ / 64) {        // next K tile -> regs (latency overlapped)
      kr0 = *(const bf16x8*)(Kh + (size_t)((kt + 1) * 64 + r0) * HD + ch0);
      kr1 = *(const bf16x8*)(Kh + (size_t)((kt + 1) * 64 + 32 + r0) * HD + ch0);
    }
    // V fragments: direct b128 from swizzled V^T, issued before score MFMAs
    bf16x8 vb[4][2];
#pragma unroll
    for (int t = 0; t < 4; ++t)
#pragma unroll
      for (int g = 0; g < 2; ++g)
        vb[t][g] = *(const bf16x8*)(Vh + (size_t)(t * 16 + c) * SEQ +
                                    kt * 64 + g * 32 + q * 8);

#pragma unroll
    for (int g = 0; g < 2; ++g) {
      bf16x4 pk[2];
#pragma unroll
      for (int s2 = 0; s2 < 2; ++s2) {
        const int s = g * 2 + s2;
        bf16x8 k0f = *(const bf16x8*)(&Kt[p][s * 16 + c][q * 8]);
        bf16x8 k1f = *(const bf16x8*)(&Kt[p][s * 16 + c][32 + q * 8]);
        f32x4 z = {0.f, 0.f, 0.f, 0.f};
        z = __builtin_amdgcn_mfma_f32_16x16x32_bf16(k0f, qfl, z, 0, 0, 0);
        z = __builtin_amdgcn_mfma_f32_16x16x32_bf16(k1f, qfh, z, 0, 0, 0);
#pragma unroll
        for (int r = 0; r < 4; ++r) {
          float pv = __builtin_amdgcn_exp2f(z[r]);
          l += pv;
          pk[s2][r] = (short)(__builtin_bit_cast(unsigned int, pv) >> 16);
        }
      }
#pragma unroll
      for (int t = 0; t < 4; ++t) {
        bf16x8 pf;
#pragma unroll
        for (int e = 0; e < 4; ++e) { pf[e] = pk[0][e]; pf[4 + e] = pk[1][e]; }
        o[t] = __builtin_amdgcn_mfma_f32_16x16x32_bf16(pf, vb[t][g], o[t], 0, 0, 0);
      }
    }

    if (kt + 1 < SEQ / 64) {
      *(bf16x8*)(&Kt[1 - p][r0][ch0]) = kr0;
      *(bf16x8*)(&Kt[1 - p][32 + r0][ch0]) = kr1;
    }
  }

  float ls = l;
  ls += __shfl_xor(ls, 16);
  ls += __shfl_xor(ls, 32);
  float lf[4];
#pragma unroll
  for (int r = 0; r < 4; ++r) lf[r] = 1.f / __shfl(ls, q * 4 + r);
#pragma unroll
  for (int t = 0; t < 4; ++t)
#pragma unroll
    for (int r = 0; r < 4; ++r) {
      int srow = q0 + q * 4 + r;
      int col = h * HD + t * 16 + c;
      float val = o[t][r] * lf[r];
      if (isnan(val)) val = 77.0f;  // marker
      Ob[((size_t)(b * SEQ + srow)) * EMBED + col] = f2bf(val);
    }
}

// ---- fallback GEMM (direct global loads; fp32 inputs) ----
__device__ inline bf16x8 load8f(const float* f) {
  bf16x8 r;
#pragma unroll
  for (int i = 0; i < 8; ++i) r[i] = (short)f2bf(f[i]);
  return r;
}
__global__ __launch_bounds__(256) void gemm_bt(
    const void* __restrict__ A, const void* __restrict__ Bw,
    const float* __restrict__ bias, void* __restrict__ out,
    int mode, float scale)
{
  const int lane = threadIdx.x & 63;
  const int wave = threadIdx.x >> 6;
  const int tile = blockIdx.x * 4 + wave;
  const int mt = tile >> 4, nt = tile & 15;
  const int q = lane >> 4, c = lane & 15;
  const int m0 = mt * 16, n0 = nt * 64;

  f32x4 acc[4];
#pragma unroll
  for (int t = 0; t < 4; ++t) acc[t] = (f32x4){0.f, 0.f, 0.f, 0.f};

  for (int k0 = 0; k0 < EMBED; k0 += 32) {
    bf16x8 a = (mode == 0)
        ? *(const bf16x8*)((const unsigned short*)A + (m0 + c) * EMBED + k0 + q * 8)
        : load8f((const float*)A + (m0 + c) * EMBED + k0 + q * 8);
#pragma unroll
    for (int t = 0; t < 4; ++t) {
      bf16x8 b = load8f((const float*)Bw + (size_t)(n0 + t * 16 + c) * EMBED + k0 + q * 8);
      acc[t] = __builtin_amdgcn_mfma_f32_16x16x32_bf16(a, b, acc[t], 0, 0, 0);
    }
  }
#pragma unroll
  for (int t = 0; t < 4; ++t)
#pragma unroll
    for (int r = 0; r < 4; ++r) {
      float v = acc[t][r] * scale;
      int row = m0 + q * 4 + r, col = n0 + t * 16 + c;
      if (mode == 0) {
        v += bias[col];
        ((float*)out)[(size_t)row * EMBED + col] = v;
      } else {
        int b = row >> 11, s = row & 2047, h = col >> 6, d = col & 63;
        if (mode == 1)
          ((unsigned short*)out)[(size_t)((b * NH + h) * SEQ + s) * HD + d] = f2bf(v);
        else
          ((unsigned short*)out)[(size_t)((b * NH + h) * HD + d) * SEQ + vswz_pos(s)] = f2bf(v);
      }
    }
}

extern "C" void kernel_launch(void* const* d_in, const int* in_sizes, int n_in,
                              void* d_out, int out_size, void* d_ws, size_t ws_size,
                              hipStream_t stream) {
  const float* xq = (const float*)d_in[0];
  const float* xk = (const float*)d_in[1];
  const float* xv = (const float*)d_in[2];
  const float* Wq = (const float*)d_in[3];
  const float* Wk = (const float*)d_in[4];
  const float* Wv = (const float*)d_in[5];
  const float* Wo = (const float*)d_in[6];
  const float* bo = (const float*)d_in[7];

  const size_t NEL = (size_t)BATCH * SEQ * EMBED;
  const size_t WEL = (size_t)EMBED * EMBED;
  unsigned short* base = (unsigned short*)d_ws;

  unsigned short* Xq = base;
  unsigned short* Xk = Xq + NEL;
  unsigned short* Xv = Xk + NEL;
  unsigned short* Wqb = Xv + NEL;
  unsigned short* Wkb = Wqb + WEL;
  unsigned short* Wvb = Wkb + WEL;
  unsigned short* Wob = Wvb + WEL;
  unsigned short* Q  = Wob + WEL;
  unsigned short* K  = Q + NEL;
  unsigned short* Vt = K + NEL;
  unsigned short* AO = Xq;                  // alias: Xq dead after QKV GEMM
  size_t need = (size_t)(6 * NEL + 4 * WEL) * sizeof(unsigned short);

  if (ws_size >= need) {
    PackPtrs pp;
    pp.src[0] = xq; pp.src[1] = xk; pp.src[2] = xv;
    pp.src[3] = Wq; pp.src[4] = Wk; pp.src[5] = Wv; pp.src[6] = Wo;
    pp.dst[0] = Xq; pp.dst[1] = Xk; pp.dst[2] = Xv;
    pp.dst[3] = Wqb; pp.dst[4] = Wkb; pp.dst[5] = Wvb; pp.dst[6] = Wob;
    pack_all<<<8192, 256, 0, stream>>>(pp);

    QkvArgs qa;
    qa.A[0] = Xq; qa.A[1] = Xk; qa.A[2] = Xv;
    qa.W[0] = Wqb; qa.W[1] = Wkb; qa.W[2] = Wvb;
    qa.out[0] = Q; qa.out[1] = K; qa.out[2] = Vt;
    gemm_qkv<<<dim3(32, 8, 3), 256, 0, stream>>>(qa);
    attn_kernel<<<dim3(32, NH, BATCH), 256, 0, stream>>>(Q, K, Vt, AO);
    gemm_out<<<dim3(64, 8), 256, 0, stream>>>(AO, Wob, bo, (float*)d_out);
  } else {
    unsigned short* Qf  = base;
    unsigned short* Kf  = Qf + NEL;
    unsigned short* Vtf = Kf + NEL;
    unsigned short* AOf = Vtf + NEL;
    dim3 gblk(1024, 1, 1);
    gemm_bt<<<gblk, 256, 0, stream>>>(xq, Wq, nullptr, Qf, 1, QSCALE);
    gemm_bt<<<gblk, 256, 0, stream>>>(xk, Wk, nullptr, Kf, 1, 1.0f);
    gemm_bt<<<gblk, 256, 0, stream>>>(xv, Wv, nullptr, Vtf, 2, 1.0f);
    attn_kernel<<<dim3(32, NH, BATCH), 256, 0, stream>>>(Qf, Kf, Vtf, AOf);
    gemm_bt<<<gblk, 256, 0, stream>>>(AOf, Wo, bo, d_out, 0, 1.0f);
  }
}